// Round 19
// baseline (441.996 us; speedup 1.0000x reference)
//
#include <hip/hip_runtime.h>
#include <math.h>

#define B_SZ   8
#define E_DIM  256
#define L_SEQ  4096
#define S_TOP  256
#define NHEAD  8
#define HD     32
#define NSPLIT 4
#define JSPL   8

typedef __attribute__((ext_vector_type(8))) short bf16x8;   // MFMA A/B frag (16B)
typedef __attribute__((ext_vector_type(4))) float f32x4;    // MFMA C/D frag

// async global->LDS, 16B per lane; LDS dest must be wave-linear (base+lane*16)
#define GLDS16(gsrc, ldst) __builtin_amdgcn_global_load_lds( \
    (const __attribute__((address_space(1))) void*)(gsrc),   \
    (__attribute__((address_space(3))) void*)(ldst), 16, 0, 0)

// round-to-nearest-even fp32 -> bf16
__device__ inline short f2bf(float x) {
    union { float f; unsigned u; } v; v.f = x;
    unsigned r = (v.u + 0x7fff + ((v.u >> 16) & 1)) >> 16;
    return (short)r;
}
__device__ inline float bf2f(short h) {
    union { unsigned u; float f; } c; c.u = ((unsigned)(unsigned short)h) << 16;
    return c.f;
}

// ---------------------------------------------------------------------------
// K_prep: gather + qconv + wconv fused (verified).
// grid 4352 = 2048 (gather) + 2048 (qconv) + 256 (wconv).
// ---------------------------------------------------------------------------
__global__ __launch_bounds__(256) void k_prep(const float* __restrict__ query,
                                              const int* __restrict__ ind,
                                              const float* __restrict__ wq,
                                              const float* __restrict__ wo,
                                              float* __restrict__ qs_pack,
                                              short* __restrict__ wqhi,
                                              short* __restrict__ wqlo,
                                              short* __restrict__ wohi,
                                              short* __restrict__ wolo,
                                              short* __restrict__ qhi,
                                              short* __restrict__ qlo) {
    __shared__ float T[64][68];                 // used by qconv section only
    const int blk = blockIdx.x;
    if (blk < 2048) {                           // --- gather ---
        int t = blk * 256 + threadIdx.x;        // over B*S*E = 524288
        int e = t & (E_DIM - 1);
        int s = (t >> 8) & (S_TOP - 1);
        int b = t >> 16;
        int idx = ind[b * S_TOP + s];
        qs_pack[t] = query[((size_t)b * E_DIM + e) * L_SEQ + idx];
        return;
    }
    if (blk >= 4096) {                          // --- wconv ---
        int t = (blk - 4096) * 256 + threadIdx.x;   // 0..65535
        float xq = wq[t];
        short hq = f2bf(xq);
        wqhi[t] = hq;
        wqlo[t] = f2bf(xq - bf2f(hq));
        float xo = wo[t];
        short ho = f2bf(xo);
        wohi[t] = ho;
        wolo[t] = f2bf(xo - bf2f(ho));
        return;
    }
    // --- qconv: transpose+split query [b][e][l] -> qhi/qlo [b][l][e] ---
    const int idx = blk - 2048;                 // 0..2047
    const int b  = idx >> 8;
    const int e0 = ((idx >> 6) & 3) * 64;
    const int l0 = (idx & 63) * 64;
    const float* src = query + ((size_t)b * E_DIM + e0) * L_SEQ + l0;
#pragma unroll
    for (int r = 0; r < 4; ++r) {
        int i2 = threadIdx.x + 256 * r;         // 0..1023
        int e = i2 >> 4, l4 = (i2 & 15) * 4;
        *(float4*)&T[e][l4] = *(const float4*)(src + (size_t)e * L_SEQ + l4);
    }
    __syncthreads();
    const int l  = threadIdx.x >> 2;            // 0..63
    const int ec = (threadIdx.x & 3) * 16;      // 0,16,32,48
    size_t dst = ((size_t)b * L_SEQ + l0 + l) * E_DIM + e0 + ec;
    bf16x8 h0, h1, lo0, lo1;
#pragma unroll
    for (int k = 0; k < 8; ++k) {
        float x = T[ec + k][l];
        short h = f2bf(x);
        h0[k] = h; lo0[k] = f2bf(x - bf2f(h));
    }
#pragma unroll
    for (int k = 0; k < 8; ++k) {
        float x = T[ec + 8 + k][l];
        short h = f2bf(x);
        h1[k] = h; lo1[k] = f2bf(x - bf2f(h));
    }
    *(bf16x8*)(qhi + dst)     = h0;
    *(bf16x8*)(qhi + dst + 8) = h1;
    *(bf16x8*)(qlo + dst)     = lo0;
    *(bf16x8*)(qlo + dst + 8) = lo1;
}

// ---------------------------------------------------------------------------
// K1: async-LDS double-buffered L1-distance, VERIFIED at 97.5us with clean
// spill + clean conflicts (VALU-issue floor for this algorithm).
// DIAGNOSTIC SPLIT: launched twice with ss0={0,2}, grid (64, 2, 8) each ->
// two ~49us dispatches, bit-identical outputs. Purpose: lower the top-5
// ceiling so the profile reveals the true #2..#5 kernels (77% of runtime
// has never been visible). Body unchanged from round-15.
// ---------------------------------------------------------------------------
__global__ __launch_bounds__(256) void k_dist(const float* __restrict__ keys,
                                              const float* __restrict__ qs_pack,
                                              double* __restrict__ minpart,
                                              int ss0) {
    const int b  = blockIdx.z;
    const int ss = blockIdx.y + ss0;
    const int l0 = blockIdx.x * 64;
    const int lid = threadIdx.x;
    const int tx = lid & 15;
    const int ty = lid >> 4;
    __shared__ float Ks[2][32][64];             // 16 KB, off = 16*f4 per buf
    __shared__ float Qs[2][64][32];             // 16 KB, bank-swizzled content
    double (*red)[64] = (double(*)[64])&Ks[0][0][0];   // 8 KB overlay on buf0

    const float* kb = keys + (size_t)b * E_DIM * L_SEQ + l0;
    const float* qb = qs_pack + ((size_t)b * S_TOP + ss * 64) * E_DIM;

    double d[4][4];
#pragma unroll
    for (int i = 0; i < 4; ++i)
#pragma unroll
        for (int j = 0; j < 4; ++j) d[i][j] = 0.0;

    {   // issue chunk-0 loads into buf 0 (Qs source pre-swizzled)
#pragma unroll
        for (int r = 0; r < 2; ++r) {
            int f4 = lid + 256 * r;
            int e  = f4 >> 4, l4 = (f4 & 15) * 4;
            GLDS16(kb + (size_t)e * L_SEQ + l4, &Ks[0][e][l4]);
            int s  = f4 >> 3, e4 = (f4 & 7) * 4;
            int el = e4 ^ (((s >> 2) & 7) << 2);    // logical col for phys e4
            GLDS16(qb + (size_t)s * E_DIM + el, &Qs[0][s][e4]);
        }
    }

    int buf = 0;
    for (int c0 = 0; c0 < E_DIM; c0 += 32, buf ^= 1) {
        __syncthreads();                        // drains vmcnt: chunk-c data
                                                // in LDS; prior compute done
        if (c0 + 32 < E_DIM) {                  // issue c+1 into other buffer;
            const int cn = c0 + 32;             // flies during compute below
            const int nb = buf ^ 1;
#pragma unroll
            for (int r = 0; r < 2; ++r) {
                int f4 = lid + 256 * r;
                int e  = f4 >> 4, l4 = (f4 & 15) * 4;
                GLDS16(kb + (size_t)(cn + e) * L_SEQ + l4, &Ks[nb][e][l4]);
                int s  = f4 >> 3, e4 = (f4 & 7) * 4;
                int el = e4 ^ (((s >> 2) & 7) << 2);
                GLDS16(qb + (size_t)s * E_DIM + cn + el, &Qs[nb][s][e4]);
            }
        }

        float cs[4][4] = {};                    // 16 indep fp32 chains
#pragma unroll
        for (int e4 = 0; e4 < 32; e4 += 4) {
            float qv[4][4];
#pragma unroll
            for (int j = 0; j < 4; ++j) {       // swizzled b128 reads: the 4
                const int row = ty * 4 + j;     // ty-groups hit disjoint banks
                float4 q = *(const float4*)&Qs[buf][row][e4 ^ (((row >> 2) & 7) << 2)];
                qv[j][0] = q.x; qv[j][1] = q.y; qv[j][2] = q.z; qv[j][3] = q.w;
            }
#pragma unroll
            for (int ee = 0; ee < 4; ++ee) {    // e ascending: e4+0,1,2,3
                float kv[4];
#pragma unroll
                for (int i = 0; i < 4; ++i) kv[i] = Ks[buf][e4 + ee][tx * 4 + i];
#pragma unroll
                for (int i = 0; i < 4; ++i)
#pragma unroll
                    for (int j = 0; j < 4; ++j)
                        cs[i][j] += fabsf(kv[i] - qv[j][ee]);
            }
        }
#pragma unroll
        for (int i = 0; i < 4; ++i)
#pragma unroll
            for (int j = 0; j < 4; ++j) d[i][j] += (double)cs[i][j];
    }

    // per-thread exact f64 min over its 4 s
    double md[4];
#pragma unroll
    for (int i = 0; i < 4; ++i) {
        double m = d[i][0];
        m = fmin(m, d[i][1]);
        m = fmin(m, d[i][2]);
        m = fmin(m, d[i][3]);
        md[i] = m;
    }
    __syncthreads();                            // all buf reads done
#pragma unroll
    for (int i = 0; i < 4; ++i) red[ty][tx * 4 + i] = md[i];
    __syncthreads();
    if (lid < 64) {                             // cross-thread min over 16 ty
        double m = red[0][lid];
#pragma unroll
        for (int t = 1; t < 16; ++t) m = fmin(m, red[t][lid]);
        minpart[((size_t)(b * NSPLIT + ss)) * L_SEQ + l0 + lid] = m;
    }
}

// ---------------------------------------------------------------------------
// K2a: partial rank (UNCHANGED)
// ---------------------------------------------------------------------------
__global__ __launch_bounds__(256) void k_rankpart(const double* __restrict__ minpart,
                                                  int* __restrict__ rankpart) {
    const int b  = blockIdx.z;
    const int js = blockIdx.y;
    const int l  = blockIdx.x * 256 + threadIdx.x;
    __shared__ double sd[512];
    const double* mp = minpart + (size_t)b * NSPLIT * L_SEQ;
    for (int jj = threadIdx.x; jj < 512; jj += 256) {
        const int j = js * 512 + jj;
        double v = mp[j];
        v = fmin(v, mp[L_SEQ + j]);
        v = fmin(v, mp[2 * L_SEQ + j]);
        v = fmin(v, mp[3 * L_SEQ + j]);
        sd[jj] = v;
    }
    double dl = mp[l];
    dl = fmin(dl, mp[L_SEQ + l]);
    dl = fmin(dl, mp[2 * L_SEQ + l]);
    dl = fmin(dl, mp[3 * L_SEQ + l]);
    __syncthreads();
    const int jbase = js * 512;
    int rank = 0;
#pragma unroll 8
    for (int jj = 0; jj < 512; ++jj) {
        double dj = sd[jj];
        rank += (dj < dl) || (dj == dl && (jbase + jj) < l) ? 1 : 0;
    }
    rankpart[((size_t)(b * JSPL + js)) * L_SEQ + l] = rank;
}

// ---------------------------------------------------------------------------
// K2b: combine ranks, scatter (UNCHANGED)
// ---------------------------------------------------------------------------
__global__ __launch_bounds__(256) void k_sel(const int* __restrict__ rankpart,
                                             int* __restrict__ sel) {
    const int t = blockIdx.x * 256 + threadIdx.x;
    const int b = t >> 12;
    const int l = t & (L_SEQ - 1);
    int r = 0;
#pragma unroll
    for (int s = 0; s < JSPL; ++s)
        r += rankpart[((size_t)(b * JSPL + s)) * L_SEQ + l];
    if (r < S_TOP) sel[b * S_TOP + r] = l;
}

// ---------------------------------------------------------------------------
// K3: K/V projection merged (UNCHANGED)
// ---------------------------------------------------------------------------
__global__ __launch_bounds__(256) void k_kvproj2(const float* __restrict__ keys,
                                                 const float* __restrict__ vals,
                                                 const int* __restrict__ sel,
                                                 const float* __restrict__ Wk,
                                                 const float* __restrict__ bk,
                                                 const float* __restrict__ Wv,
                                                 const float* __restrict__ bv,
                                                 short* __restrict__ khb,
                                                 short* __restrict__ vtb) {
    const int b  = blockIdx.z;
    const int f0 = blockIdx.x * 64;
    const int TR = blockIdx.y >> 2;
    const int k0 = (blockIdx.y & 3) * 64;
    const float* src  = TR ? vals : keys;
    const float* W    = TR ? Wv : Wk;
    const float* bias = TR ? bv : bk;
    const int tx = threadIdx.x, ty = threadIdx.y;
    const int lid = ty * 16 + tx;
    __shared__ float As[16][68];
    __shared__ float Ws[16][68];
    float c[4][4] = {};
    const float* sb = src + (size_t)b * E_DIM * L_SEQ;
    const int* selb = sel + b * S_TOP;
    for (int e0 = 0; e0 < E_DIM; e0 += 16) {
        {
            int e  = lid >> 4;
            int k4 = (lid & 15) * 4;
#pragma unroll
            for (int c2 = 0; c2 < 4; ++c2) {
                int kk = k4 + c2;
                As[e][kk] = sb[(size_t)(e0 + e) * L_SEQ + selb[k0 + kk]];
            }
        }
        {
            int f  = lid >> 2;
            int e4 = (lid & 3) * 4;
            float4 w = *(const float4*)(W + (size_t)(f0 + f) * E_DIM + e0 + e4);
            Ws[e4 + 0][f] = w.x; Ws[e4 + 1][f] = w.y;
            Ws[e4 + 2][f] = w.z; Ws[e4 + 3][f] = w.w;
        }
        __syncthreads();
#pragma unroll
        for (int e = 0; e < 16; ++e) {
            float4 a = *(const float4*)&As[e][ty * 4];
            float4 w = *(const float4*)&Ws[e][tx * 4];
            float av[4] = {a.x, a.y, a.z, a.w};
            float wv[4] = {w.x, w.y, w.z, w.w};
#pragma unroll
            for (int i = 0; i < 4; ++i)
#pragma unroll
                for (int j = 0; j < 4; ++j) c[i][j] += av[i] * wv[j];
        }
        __syncthreads();
    }
    if (TR == 0) {
#pragma unroll
        for (int i = 0; i < 4; ++i) {
            short4 o;
            o.x = f2bf(c[i][0] + bias[f0 + tx * 4 + 0]);
            o.y = f2bf(c[i][1] + bias[f0 + tx * 4 + 1]);
            o.z = f2bf(c[i][2] + bias[f0 + tx * 4 + 2]);
            o.w = f2bf(c[i][3] + bias[f0 + tx * 4 + 3]);
            *(short4*)(khb + ((size_t)b * S_TOP + k0 + ty * 4 + i) * E_DIM + f0 + tx * 4) = o;
        }
    } else {
#pragma unroll
        for (int j = 0; j < 4; ++j) {
            const float bvv = bias[f0 + tx * 4 + j];
            short4 o;
            o.x = f2bf(c[0][j] + bvv); o.y = f2bf(c[1][j] + bvv);
            o.z = f2bf(c[2][j] + bvv); o.w = f2bf(c[3][j] + bvv);
            *(short4*)(vtb + ((size_t)b * E_DIM + f0 + tx * 4 + j) * S_TOP + k0 + ty * 4) = o;
        }
    }
}

// ---------------------------------------------------------------------------
// K_qgemm: qhb[b][l][f] = bf16(scale*(q @ Wq^T + bq)) via split-bf16 MFMA
// (UNCHANGED).
// ---------------------------------------------------------------------------
__global__ __launch_bounds__(256) void k_qgemm(const short* __restrict__ qhi,
                                               const short* __restrict__ qlo,
                                               const short* __restrict__ wqhi,
                                               const short* __restrict__ wqlo,
                                               const float* __restrict__ bias,
                                               short* __restrict__ qhb,
                                               float scale) {
    const int b  = blockIdx.z;
    const int f0 = blockIdx.x * 128;
    const int l0 = blockIdx.y * 128;
    const int lid  = threadIdx.x;
    const int wv   = lid >> 6;
    const int lane = lid & 63;
    const int quad = lane >> 4;
    const int m    = lane & 15;
    const int wf   = wv >> 1;
    const int wl   = wv & 1;

    __shared__ short Awh[128 * 40];
    __shared__ short Awl[128 * 40];
    __shared__ short Bqh[128 * 40];
    __shared__ short Bql[128 * 40];

    const short* wh_g = wqhi + (size_t)f0 * E_DIM;
    const short* wl_g = wqlo + (size_t)f0 * E_DIM;
    const short* qh_g = qhi + ((size_t)b * L_SEQ + l0) * E_DIM;
    const short* ql_g = qlo + ((size_t)b * L_SEQ + l0) * E_DIM;

    f32x4 acc[4][4];
    const f32x4 zero = {0.f, 0.f, 0.f, 0.f};
#pragma unroll
    for (int i = 0; i < 4; ++i)
#pragma unroll
        for (int j = 0; j < 4; ++j) acc[i][j] = zero;

    for (int k0 = 0; k0 < E_DIM; k0 += 32) {
        __syncthreads();
#pragma unroll
        for (int r = 0; r < 2; ++r) {
            int idx = lid + 256 * r;            // 0..511
            int row = idx >> 2;
            int kc  = (idx & 3) * 8;
            *(bf16x8*)&Awh[row * 40 + kc] = *(const bf16x8*)(wh_g + (size_t)row * E_DIM + k0 + kc);
            *(bf16x8*)&Awl[row * 40 + kc] = *(const bf16x8*)(wl_g + (size_t)row * E_DIM + k0 + kc);
            *(bf16x8*)&Bqh[row * 40 + kc] = *(const bf16x8*)(qh_g + (size_t)row * E_DIM + k0 + kc);
            *(bf16x8*)&Bql[row * 40 + kc] = *(const bf16x8*)(ql_g + (size_t)row * E_DIM + k0 + kc);
        }
        __syncthreads();

        bf16x8 ah[4], al[4], bh[4], bl[4];
#pragma unroll
        for (int tf = 0; tf < 4; ++tf) {
            int row = wf * 64 + tf * 16 + m;
            ah[tf] = *(const bf16x8*)&Awh[row * 40 + quad * 8];
            al[tf] = *(const bf16x8*)&Awl[row * 40 + quad * 8];
        }
#pragma unroll
        for (int tl = 0; tl < 4; ++tl) {
            int row = wl * 64 + tl * 16 + m;
            bh[tl] = *(const bf16x8*)&Bqh[row * 40 + quad * 8];
            bl[tl] = *(const bf16x8*)&Bql[row * 40 + quad * 8];
        }
#pragma unroll
        for (int tf = 0; tf < 4; ++tf)
#pragma unroll
            for (int tl = 0; tl < 4; ++tl) {
                acc[tf][tl] = __builtin_amdgcn_mfma_f32_16x16x32_bf16(al[tf], bh[tl], acc[tf][tl], 0, 0, 0);
                acc[tf][tl] = __builtin_amdgcn_mfma_f32_16x16x32_bf16(ah[tf], bl[tl], acc[tf][tl], 0, 0, 0);
                acc[tf][tl] = __builtin_amdgcn_mfma_f32_16x16x32_bf16(ah[tf], bh[tl], acc[tf][tl], 0, 0, 0);
            }
    }

#pragma unroll
    for (int tf = 0; tf < 4; ++tf) {
        const int fb = f0 + wf * 64 + tf * 16 + quad * 4;
        float bv0 = bias[fb + 0], bv1 = bias[fb + 1];
        float bv2 = bias[fb + 2], bv3 = bias[fb + 3];
#pragma unroll
        for (int tl = 0; tl < 4; ++tl) {
            const int l = l0 + wl * 64 + tl * 16 + m;
            short4 o;
            o.x = f2bf(scale * (acc[tf][tl][0] + bv0));
            o.y = f2bf(scale * (acc[tf][tl][1] + bv1));
            o.z = f2bf(scale * (acc[tf][tl][2] + bv2));
            o.w = f2bf(scale * (acc[tf][tl][3] + bv3));
            *(short4*)(qhb + ((size_t)b * L_SEQ + l) * E_DIM + fb) = o;
        }
    }
}

// ---------------------------------------------------------------------------
// K4: bf16 MFMA flash attention; epilogue writes split bf16 hi/lo (UNCHANGED).
// ---------------------------------------------------------------------------
__global__ __launch_bounds__(256) void k_attn(const short* __restrict__ qhb,
                                              const short* __restrict__ khb,
                                              const short* __restrict__ vtb,
                                              short* __restrict__ ohi,
                                              short* __restrict__ olo) {
    __shared__ short P[4][16][264];
    const int b = blockIdx.z, h = blockIdx.y;
    const int wv   = threadIdx.x >> 6;
    const int lane = threadIdx.x & 63;
    const int quad = lane >> 4;
    const int m    = lane & 15;
    const int l0 = blockIdx.x * 64 + wv * 16;

    const short* qp = qhb + ((size_t)b * L_SEQ + l0 + m) * E_DIM + h * HD + quad * 8;
    const bf16x8 qa = *(const bf16x8*)qp;

    const short* kb = khb + (size_t)b * S_TOP * E_DIM + h * HD + quad * 8;
    f32x4 sacc[16];
    const f32x4 zero = {0.f, 0.f, 0.f, 0.f};
#pragma unroll
    for (int t = 0; t < 16; ++t) {
        bf16x8 kf = *(const bf16x8*)(kb + (size_t)(t * 16 + m) * E_DIM);
        sacc[t] = __builtin_amdgcn_mfma_f32_16x16x32_bf16(qa, kf, zero, 0, 0, 0);
    }

    float mx[4], ssum[4];
#pragma unroll
    for (int r = 0; r < 4; ++r) {
        float v = sacc[0][r];
#pragma unroll
        for (int t = 1; t < 16; ++t) v = fmaxf(v, sacc[t][r]);
#pragma unroll
        for (int off = 1; off < 16; off <<= 1) v = fmaxf(v, __shfl_xor(v, off, 16));
        mx[r] = v;
        ssum[r] = 0.f;
    }
#pragma unroll
    for (int t = 0; t < 16; ++t) {
#pragma unroll
        for (int r = 0; r < 4; ++r) {
            float p = __expf(sacc[t][r] - mx[r]);
            ssum[r] += p;
            P[wv][quad * 4 + r][t * 16 + m] = f2bf(p);
        }
    }
#pragma unroll
    for (int r = 0; r < 4; ++r) {
        float v = ssum[r];
#pragma unroll
        for (int off = 1; off < 16; off <<= 1) v += __shfl_xor(v, off, 16);
        ssum[r] = v;
    }

    const short* vb = vtb + ((size_t)b * E_DIM + h * HD) * S_TOP;
    f32x4 oacc[2];
#pragma unroll
    for (int dt = 0; dt < 2; ++dt) {
        f32x4 acc = zero;
#pragma unroll
        for (int k0 = 0; k0 < S_TOP; k0 += 32) {
            bf16x8 pa = *(const bf16x8*)&P[wv][m][k0 + quad * 8];
            bf16x8 vf = *(const bf16x8*)(vb + (size_t)(dt * 16 + m) * S_TOP + k0 + quad * 8);
            acc = __builtin_amdgcn_mfma_f32_16x16x32_bf16(pa, vf, acc, 0, 0, 0);
        }
        oacc[dt] = acc;
    }

    short* oph = ohi + ((size_t)b * L_SEQ + l0) * E_DIM + h * HD;
    short* opl = olo + ((size_t)b * L_SEQ + l0) * E_DIM + h * HD;
#pragma unroll
    for (int r = 0; r < 4; ++r) {
        const float inv = 1.0f / ssum[r];
#pragma unroll
        for (int dt = 0; dt < 2; ++dt) {
            float val = oacc[dt][r] * inv;
            short hh = f2bf(val);
            size_t off = (size_t)(quad * 4 + r) * E_DIM + dt * 16 + m;
            oph[off] = hh;
            opl[off] = f2bf(val - bf2f(hh));
        }
    }
}

// ---------------------------------------------------------------------------
// K_ogemm: out[b][f][l] = o @ Wout^T + b_out via split-bf16 MFMA (UNCHANGED).
// ---------------------------------------------------------------------------
__global__ __launch_bounds__(256) void k_ogemm(const short* __restrict__ ohi,
                                               const short* __restrict__ olo,
                                               const short* __restrict__ wohi,
                                               const short* __restrict__ wolo,
                                               const float* __restrict__ bias,
                                               float* __restrict__ out) {
    const int b  = blockIdx.z;
    const int f0 = blockIdx.x * 128;
    const int l0 = blockIdx.y * 128;
    const int lid  = threadIdx.x;
    const int wv   = lid >> 6;
    const int lane = lid & 63;
    const int quad = lane >> 4;
    const int m    = lane & 15;
    const int wl   = wv >> 1;
    const int wf   = wv & 1;

    __shared__ short Aoh[128 * 40];
    __shared__ short Aol[128 * 40];
    __shared__ short Bwh[128 * 40];
    __shared__ short Bwl[128 * 40];

    const short* oh_g = ohi + ((size_t)b * L_SEQ + l0) * E_DIM;
    const short* ol_g = olo + ((size_t)b * L_SEQ + l0) * E_DIM;
    const short* wh_g = wohi + (size_t)f0 * E_DIM;
    const short* wl_g = wolo + (size_t)f0 * E_DIM;

    f32x4 acc[4][4];
    const f32x4 zero = {0.f, 0.f, 0.f, 0.f};
#pragma unroll
    for (int i = 0; i < 4; ++i)
#pragma unroll
        for (int j = 0; j < 4; ++j) acc[i][j] = zero;

    for (int k0 = 0; k0 < E_DIM; k0 += 32) {
        __syncthreads();
#pragma unroll
        for (int r = 0; r < 2; ++r) {
            int idx = lid + 256 * r;
            int row = idx >> 2;
            int kc  = (idx & 3) * 8;
            *(bf16x8*)&Aoh[row * 40 + kc] = *(const bf16x8*)(oh_g + (size_t)row * E_DIM + k0 + kc);
            *(bf16x8*)&Aol[row * 40 + kc] = *(const bf16x8*)(ol_g + (size_t)row * E_DIM + k0 + kc);
            *(bf16x8*)&Bwh[row * 40 + kc] = *(const bf16x8*)(wh_g + (size_t)row * E_DIM + k0 + kc);
            *(bf16x8*)&Bwl[row * 40 + kc] = *(const bf16x8*)(wl_g + (size_t)row * E_DIM + k0 + kc);
        }
        __syncthreads();

        bf16x8 ah[4], al[4], bh[4], bl[4];
#pragma unroll
        for (int tl = 0; tl < 4; ++tl) {
            int row = wl * 64 + tl * 16 + m;
            ah[tl] = *(const bf16x8*)&Aoh[row * 40 + quad * 8];
            al[tl] = *(const bf16x8*)&Aol[row * 40 + quad * 8];
        }
#pragma unroll
        for (int tf = 0; tf < 4; ++tf) {
            int row = wf * 64 + tf * 16 + m;
            bh[tf] = *(const bf16x8*)&Bwh[row * 40 + quad * 8];
            bl[tf] = *(const bf16x8*)&Bwl[row * 40 + quad * 8];
        }
#pragma unroll
        for (int tl = 0; tl < 4; ++tl)
#pragma unroll
            for (int tf = 0; tf < 4; ++tf) {
                acc[tl][tf] = __builtin_amdgcn_mfma_f32_16x16x32_bf16(al[tl], bh[tf], acc[tl][tf], 0, 0, 0);
                acc[tl][tf] = __builtin_amdgcn_mfma_f32_16x16x32_bf16(ah[tl], bl[tf], acc[tl][tf], 0, 0, 0);
                acc[tl][tf] = __builtin_amdgcn_mfma_f32_16x16x32_bf16(ah[tl], bh[tf], acc[tl][tf], 0, 0, 0);
            }
    }

#pragma unroll
    for (int tl = 0; tl < 4; ++tl) {
        const int lb = l0 + wl * 64 + tl * 16 + quad * 4;
#pragma unroll
        for (int tf = 0; tf < 4; ++tf) {
            const int f = f0 + wf * 64 + tf * 16 + m;
            const float bv = bias[f];
            float4 o;
            o.x = acc[tl][tf][0] + bv;
            o.y = acc[tl][tf][1] + bv;
            o.z = acc[tl][tf][2] + bv;
            o.w = acc[tl][tf][3] + bv;
            *(float4*)(out + ((size_t)b * E_DIM + f) * L_SEQ + lb) = o;
        }
    }
}

// ---------------------------------------------------------------------------
extern "C" void kernel_launch(void* const* d_in, const int* in_sizes, int n_in,
                              void* d_out, int out_size, void* d_ws, size_t ws_size,
                              hipStream_t stream) {
    const float* query = (const float*)d_in[0];
    const float* keys  = (const float*)d_in[1];
    const float* vals  = (const float*)d_in[2];
    const int*   rind  = (const int*)d_in[3];
    const float* ipw   = (const float*)d_in[4];
    const float* ipb   = (const float*)d_in[5];
    const float* opw   = (const float*)d_in[6];
    const float* opb   = (const float*)d_in[7];
    float* out = (float*)d_out;

    char* ws = (char*)d_ws;
    const size_t MI = 1024 * 1024;
    float*  qs_pack  = (float*)(ws + 0);             //  2 MiB
    double* minpart  = (double*)(ws + 2 * MI);       //  1 MiB
    int*    sel      = (int*)   (ws + 3 * MI);       //  8 KiB
    short*  khb      = (short*) (ws + 4 * MI);       //  1 MiB
    int*    rankpart = (int*)   (ws + 5 * MI);       //  1 MiB
    short*  vtb      = (short*) (ws + 6 * MI);       //  1 MiB
    short*  wqhi     = (short*) (ws + 7 * MI);       // 128 KiB
    short*  wqlo     = (short*) (ws + 7 * MI + 131072);
    short*  wohi     = (short*) (ws + 7 * MI + 2 * 131072);
    short*  wolo     = (short*) (ws + 7 * MI + 3 * 131072);
    short*  qhb      = (short*) (ws + 8 * MI);       // 16 MiB, live qgemm->attn
    short*  qhi      = (short*) (ws + 24 * MI);      // 16 MiB, dead after qgemm
    short*  qlo      = (short*) (ws + 40 * MI);      // 16 MiB, dead after qgemm
    short*  ohi      = (short*) (ws + 24 * MI);      // overlaps qhi (attn writes after qgemm)
    short*  olo      = (short*) (ws + 40 * MI);      // overlaps qlo

    const float scale = 0.17677669529663687f;  // 32^-0.5

    k_prep<<<dim3(4352), 256, 0, stream>>>(query, rind, ipw, opw, qs_pack,
                                           wqhi, wqlo, wohi, wolo, qhi, qlo);
    k_dist<<<dim3(L_SEQ / 64, NSPLIT / 2, B_SZ), dim3(256), 0, stream>>>(keys, qs_pack, minpart, 0);
    k_dist<<<dim3(L_SEQ / 64, NSPLIT / 2, B_SZ), dim3(256), 0, stream>>>(keys, qs_pack, minpart, 2);
    k_rankpart<<<dim3(L_SEQ / 256, JSPL, B_SZ), 256, 0, stream>>>(minpart, rankpart);
    k_sel<<<dim3((B_SZ * L_SEQ) / 256), 256, 0, stream>>>(rankpart, sel);
    k_kvproj2<<<dim3(E_DIM / 64, 2 * (S_TOP / 64), B_SZ), dim3(16, 16), 0, stream>>>(
        keys, vals, sel,
        ipw + (size_t)E_DIM * E_DIM, ipb + E_DIM,
        ipw + (size_t)2 * E_DIM * E_DIM, ipb + 2 * E_DIM,
        khb, vtb);
    k_qgemm<<<dim3(E_DIM / 128, L_SEQ / 128, B_SZ), 256, 0, stream>>>(
        qhi, qlo, wqhi, wqlo, ipb, qhb, scale);
    k_attn<<<dim3(L_SEQ / 64, NHEAD, B_SZ), 256, 0, stream>>>(qhb, khb, vtb, ohi, olo);
    k_ogemm<<<dim3(E_DIM / 128, L_SEQ / 128, B_SZ), 256, 0, stream>>>(
        ohi, olo, wohi, wolo, opb, out);
}

// Round 20
// 432.447 us; speedup vs baseline: 1.0221x; 1.0221x over previous
//
#include <hip/hip_runtime.h>
#include <math.h>

#define B_SZ   8
#define E_DIM  256
#define L_SEQ  4096
#define S_TOP  256
#define NHEAD  8
#define HD     32
#define NSPLIT 4
#define JSPL   8

typedef __attribute__((ext_vector_type(8))) short bf16x8;   // MFMA A/B frag (16B)
typedef __attribute__((ext_vector_type(4))) float f32x4;    // MFMA C/D frag

// async global->LDS, 16B per lane; LDS dest must be wave-linear (base+lane*16)
#define GLDS16(gsrc, ldst) __builtin_amdgcn_global_load_lds( \
    (const __attribute__((address_space(1))) void*)(gsrc),   \
    (__attribute__((address_space(3))) void*)(ldst), 16, 0, 0)

// round-to-nearest-even fp32 -> bf16
__device__ inline short f2bf(float x) {
    union { float f; unsigned u; } v; v.f = x;
    unsigned r = (v.u + 0x7fff + ((v.u >> 16) & 1)) >> 16;
    return (short)r;
}
__device__ inline float bf2f(short h) {
    union { unsigned u; float f; } c; c.u = ((unsigned)(unsigned short)h) << 16;
    return c.f;
}

// ---------------------------------------------------------------------------
// K_prep: gather + qconv + wconv fused (verified).
// grid 4352 = 2048 (gather) + 2048 (qconv) + 256 (wconv).
// ---------------------------------------------------------------------------
__global__ __launch_bounds__(256) void k_prep(const float* __restrict__ query,
                                              const int* __restrict__ ind,
                                              const float* __restrict__ wq,
                                              const float* __restrict__ wo,
                                              float* __restrict__ qs_pack,
                                              short* __restrict__ wqhi,
                                              short* __restrict__ wqlo,
                                              short* __restrict__ wohi,
                                              short* __restrict__ wolo,
                                              short* __restrict__ qhi,
                                              short* __restrict__ qlo) {
    __shared__ float T[64][68];                 // used by qconv section only
    const int blk = blockIdx.x;
    if (blk < 2048) {                           // --- gather ---
        int t = blk * 256 + threadIdx.x;        // over B*S*E = 524288
        int e = t & (E_DIM - 1);
        int s = (t >> 8) & (S_TOP - 1);
        int b = t >> 16;
        int idx = ind[b * S_TOP + s];
        qs_pack[t] = query[((size_t)b * E_DIM + e) * L_SEQ + idx];
        return;
    }
    if (blk >= 4096) {                          // --- wconv ---
        int t = (blk - 4096) * 256 + threadIdx.x;   // 0..65535
        float xq = wq[t];
        short hq = f2bf(xq);
        wqhi[t] = hq;
        wqlo[t] = f2bf(xq - bf2f(hq));
        float xo = wo[t];
        short ho = f2bf(xo);
        wohi[t] = ho;
        wolo[t] = f2bf(xo - bf2f(ho));
        return;
    }
    // --- qconv: transpose+split query [b][e][l] -> qhi/qlo [b][l][e] ---
    const int idx = blk - 2048;                 // 0..2047
    const int b  = idx >> 8;
    const int e0 = ((idx >> 6) & 3) * 64;
    const int l0 = (idx & 63) * 64;
    const float* src = query + ((size_t)b * E_DIM + e0) * L_SEQ + l0;
#pragma unroll
    for (int r = 0; r < 4; ++r) {
        int i2 = threadIdx.x + 256 * r;         // 0..1023
        int e = i2 >> 4, l4 = (i2 & 15) * 4;
        *(float4*)&T[e][l4] = *(const float4*)(src + (size_t)e * L_SEQ + l4);
    }
    __syncthreads();
    const int l  = threadIdx.x >> 2;            // 0..63
    const int ec = (threadIdx.x & 3) * 16;      // 0,16,32,48
    size_t dst = ((size_t)b * L_SEQ + l0 + l) * E_DIM + e0 + ec;
    bf16x8 h0, h1, lo0, lo1;
#pragma unroll
    for (int k = 0; k < 8; ++k) {
        float x = T[ec + k][l];
        short h = f2bf(x);
        h0[k] = h; lo0[k] = f2bf(x - bf2f(h));
    }
#pragma unroll
    for (int k = 0; k < 8; ++k) {
        float x = T[ec + 8 + k][l];
        short h = f2bf(x);
        h1[k] = h; lo1[k] = f2bf(x - bf2f(h));
    }
    *(bf16x8*)(qhi + dst)     = h0;
    *(bf16x8*)(qhi + dst + 8) = h1;
    *(bf16x8*)(qlo + dst)     = lo0;
    *(bf16x8*)(qlo + dst + 8) = lo1;
}

// ---------------------------------------------------------------------------
// K1: async-LDS double-buffered L1-distance (round-15 verified, 97.5us,
// clean counters, VALU-issue floor). Diagnostic split REVERTED (purpose
// served; it cost ~13us launch overhead). Single launch (64, NSPLIT, 8).
// ---------------------------------------------------------------------------
__global__ __launch_bounds__(256) void k_dist(const float* __restrict__ keys,
                                              const float* __restrict__ qs_pack,
                                              double* __restrict__ minpart) {
    const int b  = blockIdx.z;
    const int ss = blockIdx.y;
    const int l0 = blockIdx.x * 64;
    const int lid = threadIdx.x;
    const int tx = lid & 15;
    const int ty = lid >> 4;
    __shared__ float Ks[2][32][64];             // 16 KB, off = 16*f4 per buf
    __shared__ float Qs[2][64][32];             // 16 KB, bank-swizzled content
    double (*red)[64] = (double(*)[64])&Ks[0][0][0];   // 8 KB overlay on buf0

    const float* kb = keys + (size_t)b * E_DIM * L_SEQ + l0;
    const float* qb = qs_pack + ((size_t)b * S_TOP + ss * 64) * E_DIM;

    double d[4][4];
#pragma unroll
    for (int i = 0; i < 4; ++i)
#pragma unroll
        for (int j = 0; j < 4; ++j) d[i][j] = 0.0;

    {   // issue chunk-0 loads into buf 0 (Qs source pre-swizzled)
#pragma unroll
        for (int r = 0; r < 2; ++r) {
            int f4 = lid + 256 * r;
            int e  = f4 >> 4, l4 = (f4 & 15) * 4;
            GLDS16(kb + (size_t)e * L_SEQ + l4, &Ks[0][e][l4]);
            int s  = f4 >> 3, e4 = (f4 & 7) * 4;
            int el = e4 ^ (((s >> 2) & 7) << 2);    // logical col for phys e4
            GLDS16(qb + (size_t)s * E_DIM + el, &Qs[0][s][e4]);
        }
    }

    int buf = 0;
    for (int c0 = 0; c0 < E_DIM; c0 += 32, buf ^= 1) {
        __syncthreads();                        // drains vmcnt: chunk-c data
                                                // in LDS; prior compute done
        if (c0 + 32 < E_DIM) {                  // issue c+1 into other buffer;
            const int cn = c0 + 32;             // flies during compute below
            const int nb = buf ^ 1;
#pragma unroll
            for (int r = 0; r < 2; ++r) {
                int f4 = lid + 256 * r;
                int e  = f4 >> 4, l4 = (f4 & 15) * 4;
                GLDS16(kb + (size_t)(cn + e) * L_SEQ + l4, &Ks[nb][e][l4]);
                int s  = f4 >> 3, e4 = (f4 & 7) * 4;
                int el = e4 ^ (((s >> 2) & 7) << 2);
                GLDS16(qb + (size_t)s * E_DIM + cn + el, &Qs[nb][s][e4]);
            }
        }

        float cs[4][4] = {};                    // 16 indep fp32 chains
#pragma unroll
        for (int e4 = 0; e4 < 32; e4 += 4) {
            float qv[4][4];
#pragma unroll
            for (int j = 0; j < 4; ++j) {       // swizzled b128 reads: the 4
                const int row = ty * 4 + j;     // ty-groups hit disjoint banks
                float4 q = *(const float4*)&Qs[buf][row][e4 ^ (((row >> 2) & 7) << 2)];
                qv[j][0] = q.x; qv[j][1] = q.y; qv[j][2] = q.z; qv[j][3] = q.w;
            }
#pragma unroll
            for (int ee = 0; ee < 4; ++ee) {    // e ascending: e4+0,1,2,3
                float kv[4];
#pragma unroll
                for (int i = 0; i < 4; ++i) kv[i] = Ks[buf][e4 + ee][tx * 4 + i];
#pragma unroll
                for (int i = 0; i < 4; ++i)
#pragma unroll
                    for (int j = 0; j < 4; ++j)
                        cs[i][j] += fabsf(kv[i] - qv[j][ee]);
            }
        }
#pragma unroll
        for (int i = 0; i < 4; ++i)
#pragma unroll
            for (int j = 0; j < 4; ++j) d[i][j] += (double)cs[i][j];
    }

    // per-thread exact f64 min over its 4 s
    double md[4];
#pragma unroll
    for (int i = 0; i < 4; ++i) {
        double m = d[i][0];
        m = fmin(m, d[i][1]);
        m = fmin(m, d[i][2]);
        m = fmin(m, d[i][3]);
        md[i] = m;
    }
    __syncthreads();                            // all buf reads done
#pragma unroll
    for (int i = 0; i < 4; ++i) red[ty][tx * 4 + i] = md[i];
    __syncthreads();
    if (lid < 64) {                             // cross-thread min over 16 ty
        double m = red[0][lid];
#pragma unroll
        for (int t = 1; t < 16; ++t) m = fmin(m, red[t][lid]);
        minpart[((size_t)(b * NSPLIT + ss)) * L_SEQ + l0 + lid] = m;
    }
}

// ---------------------------------------------------------------------------
// K2a: partial rank (UNCHANGED)
// ---------------------------------------------------------------------------
__global__ __launch_bounds__(256) void k_rankpart(const double* __restrict__ minpart,
                                                  int* __restrict__ rankpart) {
    const int b  = blockIdx.z;
    const int js = blockIdx.y;
    const int l  = blockIdx.x * 256 + threadIdx.x;
    __shared__ double sd[512];
    const double* mp = minpart + (size_t)b * NSPLIT * L_SEQ;
    for (int jj = threadIdx.x; jj < 512; jj += 256) {
        const int j = js * 512 + jj;
        double v = mp[j];
        v = fmin(v, mp[L_SEQ + j]);
        v = fmin(v, mp[2 * L_SEQ + j]);
        v = fmin(v, mp[3 * L_SEQ + j]);
        sd[jj] = v;
    }
    double dl = mp[l];
    dl = fmin(dl, mp[L_SEQ + l]);
    dl = fmin(dl, mp[2 * L_SEQ + l]);
    dl = fmin(dl, mp[3 * L_SEQ + l]);
    __syncthreads();
    const int jbase = js * 512;
    int rank = 0;
#pragma unroll 8
    for (int jj = 0; jj < 512; ++jj) {
        double dj = sd[jj];
        rank += (dj < dl) || (dj == dl && (jbase + jj) < l) ? 1 : 0;
    }
    rankpart[((size_t)(b * JSPL + js)) * L_SEQ + l] = rank;
}

// ---------------------------------------------------------------------------
// K2b: combine ranks, scatter (UNCHANGED)
// ---------------------------------------------------------------------------
__global__ __launch_bounds__(256) void k_sel(const int* __restrict__ rankpart,
                                             int* __restrict__ sel) {
    const int t = blockIdx.x * 256 + threadIdx.x;
    const int b = t >> 12;
    const int l = t & (L_SEQ - 1);
    int r = 0;
#pragma unroll
    for (int s = 0; s < JSPL; ++s)
        r += rankpart[((size_t)(b * JSPL + s)) * L_SEQ + l];
    if (r < S_TOP) sel[b * S_TOP + r] = l;
}

// ---------------------------------------------------------------------------
// K3: K/V projection merged (UNCHANGED)
// ---------------------------------------------------------------------------
__global__ __launch_bounds__(256) void k_kvproj2(const float* __restrict__ keys,
                                                 const float* __restrict__ vals,
                                                 const int* __restrict__ sel,
                                                 const float* __restrict__ Wk,
                                                 const float* __restrict__ bk,
                                                 const float* __restrict__ Wv,
                                                 const float* __restrict__ bv,
                                                 short* __restrict__ khb,
                                                 short* __restrict__ vtb) {
    const int b  = blockIdx.z;
    const int f0 = blockIdx.x * 64;
    const int TR = blockIdx.y >> 2;
    const int k0 = (blockIdx.y & 3) * 64;
    const float* src  = TR ? vals : keys;
    const float* W    = TR ? Wv : Wk;
    const float* bias = TR ? bv : bk;
    const int tx = threadIdx.x, ty = threadIdx.y;
    const int lid = ty * 16 + tx;
    __shared__ float As[16][68];
    __shared__ float Ws[16][68];
    float c[4][4] = {};
    const float* sb = src + (size_t)b * E_DIM * L_SEQ;
    const int* selb = sel + b * S_TOP;
    for (int e0 = 0; e0 < E_DIM; e0 += 16) {
        {
            int e  = lid >> 4;
            int k4 = (lid & 15) * 4;
#pragma unroll
            for (int c2 = 0; c2 < 4; ++c2) {
                int kk = k4 + c2;
                As[e][kk] = sb[(size_t)(e0 + e) * L_SEQ + selb[k0 + kk]];
            }
        }
        {
            int f  = lid >> 2;
            int e4 = (lid & 3) * 4;
            float4 w = *(const float4*)(W + (size_t)(f0 + f) * E_DIM + e0 + e4);
            Ws[e4 + 0][f] = w.x; Ws[e4 + 1][f] = w.y;
            Ws[e4 + 2][f] = w.z; Ws[e4 + 3][f] = w.w;
        }
        __syncthreads();
#pragma unroll
        for (int e = 0; e < 16; ++e) {
            float4 a = *(const float4*)&As[e][ty * 4];
            float4 w = *(const float4*)&Ws[e][tx * 4];
            float av[4] = {a.x, a.y, a.z, a.w};
            float wv[4] = {w.x, w.y, w.z, w.w};
#pragma unroll
            for (int i = 0; i < 4; ++i)
#pragma unroll
                for (int j = 0; j < 4; ++j) c[i][j] += av[i] * wv[j];
        }
        __syncthreads();
    }
    if (TR == 0) {
#pragma unroll
        for (int i = 0; i < 4; ++i) {
            short4 o;
            o.x = f2bf(c[i][0] + bias[f0 + tx * 4 + 0]);
            o.y = f2bf(c[i][1] + bias[f0 + tx * 4 + 1]);
            o.z = f2bf(c[i][2] + bias[f0 + tx * 4 + 2]);
            o.w = f2bf(c[i][3] + bias[f0 + tx * 4 + 3]);
            *(short4*)(khb + ((size_t)b * S_TOP + k0 + ty * 4 + i) * E_DIM + f0 + tx * 4) = o;
        }
    } else {
#pragma unroll
        for (int j = 0; j < 4; ++j) {
            const float bvv = bias[f0 + tx * 4 + j];
            short4 o;
            o.x = f2bf(c[0][j] + bvv); o.y = f2bf(c[1][j] + bvv);
            o.z = f2bf(c[2][j] + bvv); o.w = f2bf(c[3][j] + bvv);
            *(short4*)(vtb + ((size_t)b * E_DIM + f0 + tx * 4 + j) * S_TOP + k0 + ty * 4) = o;
        }
    }
}

// ---------------------------------------------------------------------------
// K_qgemm: qhb[b][l][f] = bf16(scale*(q @ Wq^T + bq)) via split-bf16 MFMA
// (UNCHANGED).
// ---------------------------------------------------------------------------
__global__ __launch_bounds__(256) void k_qgemm(const short* __restrict__ qhi,
                                               const short* __restrict__ qlo,
                                               const short* __restrict__ wqhi,
                                               const short* __restrict__ wqlo,
                                               const float* __restrict__ bias,
                                               short* __restrict__ qhb,
                                               float scale) {
    const int b  = blockIdx.z;
    const int f0 = blockIdx.x * 128;
    const int l0 = blockIdx.y * 128;
    const int lid  = threadIdx.x;
    const int wv   = lid >> 6;
    const int lane = lid & 63;
    const int quad = lane >> 4;
    const int m    = lane & 15;
    const int wf   = wv >> 1;
    const int wl   = wv & 1;

    __shared__ short Awh[128 * 40];
    __shared__ short Awl[128 * 40];
    __shared__ short Bqh[128 * 40];
    __shared__ short Bql[128 * 40];

    const short* wh_g = wqhi + (size_t)f0 * E_DIM;
    const short* wl_g = wqlo + (size_t)f0 * E_DIM;
    const short* qh_g = qhi + ((size_t)b * L_SEQ + l0) * E_DIM;
    const short* ql_g = qlo + ((size_t)b * L_SEQ + l0) * E_DIM;

    f32x4 acc[4][4];
    const f32x4 zero = {0.f, 0.f, 0.f, 0.f};
#pragma unroll
    for (int i = 0; i < 4; ++i)
#pragma unroll
        for (int j = 0; j < 4; ++j) acc[i][j] = zero;

    for (int k0 = 0; k0 < E_DIM; k0 += 32) {
        __syncthreads();
#pragma unroll
        for (int r = 0; r < 2; ++r) {
            int idx = lid + 256 * r;            // 0..511
            int row = idx >> 2;
            int kc  = (idx & 3) * 8;
            *(bf16x8*)&Awh[row * 40 + kc] = *(const bf16x8*)(wh_g + (size_t)row * E_DIM + k0 + kc);
            *(bf16x8*)&Awl[row * 40 + kc] = *(const bf16x8*)(wl_g + (size_t)row * E_DIM + k0 + kc);
            *(bf16x8*)&Bqh[row * 40 + kc] = *(const bf16x8*)(qh_g + (size_t)row * E_DIM + k0 + kc);
            *(bf16x8*)&Bql[row * 40 + kc] = *(const bf16x8*)(ql_g + (size_t)row * E_DIM + k0 + kc);
        }
        __syncthreads();

        bf16x8 ah[4], al[4], bh[4], bl[4];
#pragma unroll
        for (int tf = 0; tf < 4; ++tf) {
            int row = wf * 64 + tf * 16 + m;
            ah[tf] = *(const bf16x8*)&Awh[row * 40 + quad * 8];
            al[tf] = *(const bf16x8*)&Awl[row * 40 + quad * 8];
        }
#pragma unroll
        for (int tl = 0; tl < 4; ++tl) {
            int row = wl * 64 + tl * 16 + m;
            bh[tl] = *(const bf16x8*)&Bqh[row * 40 + quad * 8];
            bl[tl] = *(const bf16x8*)&Bql[row * 40 + quad * 8];
        }
#pragma unroll
        for (int tf = 0; tf < 4; ++tf)
#pragma unroll
            for (int tl = 0; tl < 4; ++tl) {
                acc[tf][tl] = __builtin_amdgcn_mfma_f32_16x16x32_bf16(al[tf], bh[tl], acc[tf][tl], 0, 0, 0);
                acc[tf][tl] = __builtin_amdgcn_mfma_f32_16x16x32_bf16(ah[tf], bl[tl], acc[tf][tl], 0, 0, 0);
                acc[tf][tl] = __builtin_amdgcn_mfma_f32_16x16x32_bf16(ah[tf], bh[tl], acc[tf][tl], 0, 0, 0);
            }
    }

#pragma unroll
    for (int tf = 0; tf < 4; ++tf) {
        const int fb = f0 + wf * 64 + tf * 16 + quad * 4;
        float bv0 = bias[fb + 0], bv1 = bias[fb + 1];
        float bv2 = bias[fb + 2], bv3 = bias[fb + 3];
#pragma unroll
        for (int tl = 0; tl < 4; ++tl) {
            const int l = l0 + wl * 64 + tl * 16 + m;
            short4 o;
            o.x = f2bf(scale * (acc[tf][tl][0] + bv0));
            o.y = f2bf(scale * (acc[tf][tl][1] + bv1));
            o.z = f2bf(scale * (acc[tf][tl][2] + bv2));
            o.w = f2bf(scale * (acc[tf][tl][3] + bv3));
            *(short4*)(qhb + ((size_t)b * L_SEQ + l) * E_DIM + fb) = o;
        }
    }
}

// ---------------------------------------------------------------------------
// K4 (round-20): bf16 MFMA flash attention, 1 WAVE PER BLOCK. Round-19 PMC:
// 74.5us, MfmaUtil 4.3%, VALUBusy 28%, Occupancy 27% -> latency-bound, LDS
// 33.8KB (4-wave P) capped residency at 4 blocks/CU. k_attn has NO barriers
// (P slices were wave-private), so 64-thread blocks are math-identical:
// P LDS 33.8KB -> 8.4KB/block, blocks/CU LDS-limit 4 -> 18 -> far more
// resident waves to hide K/V/Q load latency. grid (L/16, H, B), block 64.
// ---------------------------------------------------------------------------
__global__ __launch_bounds__(64) void k_attn(const short* __restrict__ qhb,
                                             const short* __restrict__ khb,
                                             const short* __restrict__ vtb,
                                             short* __restrict__ ohi,
                                             short* __restrict__ olo) {
    __shared__ short P[16][264];                // 8.4 KB, wave-private
    const int b = blockIdx.z, h = blockIdx.y;
    const int lane = threadIdx.x;               // 0..63
    const int quad = lane >> 4;
    const int m    = lane & 15;
    const int l0 = blockIdx.x * 16;

    const short* qp = qhb + ((size_t)b * L_SEQ + l0 + m) * E_DIM + h * HD + quad * 8;
    const bf16x8 qa = *(const bf16x8*)qp;

    const short* kb = khb + (size_t)b * S_TOP * E_DIM + h * HD + quad * 8;
    f32x4 sacc[16];
    const f32x4 zero = {0.f, 0.f, 0.f, 0.f};
#pragma unroll
    for (int t = 0; t < 16; ++t) {
        bf16x8 kf = *(const bf16x8*)(kb + (size_t)(t * 16 + m) * E_DIM);
        sacc[t] = __builtin_amdgcn_mfma_f32_16x16x32_bf16(qa, kf, zero, 0, 0, 0);
    }

    float mx[4], ssum[4];
#pragma unroll
    for (int r = 0; r < 4; ++r) {
        float v = sacc[0][r];
#pragma unroll
        for (int t = 1; t < 16; ++t) v = fmaxf(v, sacc[t][r]);
#pragma unroll
        for (int off = 1; off < 16; off <<= 1) v = fmaxf(v, __shfl_xor(v, off, 16));
        mx[r] = v;
        ssum[r] = 0.f;
    }
#pragma unroll
    for (int t = 0; t < 16; ++t) {
#pragma unroll
        for (int r = 0; r < 4; ++r) {
            float p = __expf(sacc[t][r] - mx[r]);
            ssum[r] += p;
            P[quad * 4 + r][t * 16 + m] = f2bf(p);
        }
    }
#pragma unroll
    for (int r = 0; r < 4; ++r) {
        float v = ssum[r];
#pragma unroll
        for (int off = 1; off < 16; off <<= 1) v += __shfl_xor(v, off, 16);
        ssum[r] = v;
    }

    const short* vb = vtb + ((size_t)b * E_DIM + h * HD) * S_TOP;
    f32x4 oacc[2];
#pragma unroll
    for (int dt = 0; dt < 2; ++dt) {
        f32x4 acc = zero;
#pragma unroll
        for (int k0 = 0; k0 < S_TOP; k0 += 32) {
            bf16x8 pa = *(const bf16x8*)&P[m][k0 + quad * 8];
            bf16x8 vf = *(const bf16x8*)(vb + (size_t)(dt * 16 + m) * S_TOP + k0 + quad * 8);
            acc = __builtin_amdgcn_mfma_f32_16x16x32_bf16(pa, vf, acc, 0, 0, 0);
        }
        oacc[dt] = acc;
    }

    short* oph = ohi + ((size_t)b * L_SEQ + l0) * E_DIM + h * HD;
    short* opl = olo + ((size_t)b * L_SEQ + l0) * E_DIM + h * HD;
#pragma unroll
    for (int r = 0; r < 4; ++r) {
        const float inv = 1.0f / ssum[r];
#pragma unroll
        for (int dt = 0; dt < 2; ++dt) {
            float val = oacc[dt][r] * inv;
            short hh = f2bf(val);
            size_t off = (size_t)(quad * 4 + r) * E_DIM + dt * 16 + m;
            oph[off] = hh;
            opl[off] = f2bf(val - bf2f(hh));
        }
    }
}

// ---------------------------------------------------------------------------
// K_ogemm: out[b][f][l] = o @ Wout^T + b_out via split-bf16 MFMA (UNCHANGED).
// ---------------------------------------------------------------------------
__global__ __launch_bounds__(256) void k_ogemm(const short* __restrict__ ohi,
                                               const short* __restrict__ olo,
                                               const short* __restrict__ wohi,
                                               const short* __restrict__ wolo,
                                               const float* __restrict__ bias,
                                               float* __restrict__ out) {
    const int b  = blockIdx.z;
    const int f0 = blockIdx.x * 128;
    const int l0 = blockIdx.y * 128;
    const int lid  = threadIdx.x;
    const int wv   = lid >> 6;
    const int lane = lid & 63;
    const int quad = lane >> 4;
    const int m    = lane & 15;
    const int wl   = wv >> 1;
    const int wf   = wv & 1;

    __shared__ short Aoh[128 * 40];
    __shared__ short Aol[128 * 40];
    __shared__ short Bwh[128 * 40];
    __shared__ short Bwl[128 * 40];

    const short* oh_g = ohi + ((size_t)b * L_SEQ + l0) * E_DIM;
    const short* ol_g = olo + ((size_t)b * L_SEQ + l0) * E_DIM;
    const short* wh_g = wohi + (size_t)f0 * E_DIM;
    const short* wl_g = wolo + (size_t)f0 * E_DIM;

    f32x4 acc[4][4];
    const f32x4 zero = {0.f, 0.f, 0.f, 0.f};
#pragma unroll
    for (int i = 0; i < 4; ++i)
#pragma unroll
        for (int j = 0; j < 4; ++j) acc[i][j] = zero;

    for (int k0 = 0; k0 < E_DIM; k0 += 32) {
        __syncthreads();
#pragma unroll
        for (int r = 0; r < 2; ++r) {
            int idx = lid + 256 * r;
            int row = idx >> 2;
            int kc  = (idx & 3) * 8;
            *(bf16x8*)&Aoh[row * 40 + kc] = *(const bf16x8*)(oh_g + (size_t)row * E_DIM + k0 + kc);
            *(bf16x8*)&Aol[row * 40 + kc] = *(const bf16x8*)(ol_g + (size_t)row * E_DIM + k0 + kc);
            *(bf16x8*)&Bwh[row * 40 + kc] = *(const bf16x8*)(wh_g + (size_t)row * E_DIM + k0 + kc);
            *(bf16x8*)&Bwl[row * 40 + kc] = *(const bf16x8*)(wl_g + (size_t)row * E_DIM + k0 + kc);
        }
        __syncthreads();

        bf16x8 ah[4], al[4], bh[4], bl[4];
#pragma unroll
        for (int tl = 0; tl < 4; ++tl) {
            int row = wl * 64 + tl * 16 + m;
            ah[tl] = *(const bf16x8*)&Aoh[row * 40 + quad * 8];
            al[tl] = *(const bf16x8*)&Aol[row * 40 + quad * 8];
        }
#pragma unroll
        for (int tf = 0; tf < 4; ++tf) {
            int row = wf * 64 + tf * 16 + m;
            bh[tf] = *(const bf16x8*)&Bwh[row * 40 + quad * 8];
            bl[tf] = *(const bf16x8*)&Bwl[row * 40 + quad * 8];
        }
#pragma unroll
        for (int tl = 0; tl < 4; ++tl)
#pragma unroll
            for (int tf = 0; tf < 4; ++tf) {
                acc[tl][tf] = __builtin_amdgcn_mfma_f32_16x16x32_bf16(al[tl], bh[tf], acc[tl][tf], 0, 0, 0);
                acc[tl][tf] = __builtin_amdgcn_mfma_f32_16x16x32_bf16(ah[tl], bl[tf], acc[tl][tf], 0, 0, 0);
                acc[tl][tf] = __builtin_amdgcn_mfma_f32_16x16x32_bf16(ah[tl], bh[tf], acc[tl][tf], 0, 0, 0);
            }
    }

#pragma unroll
    for (int tl = 0; tl < 4; ++tl) {
        const int lb = l0 + wl * 64 + tl * 16 + quad * 4;
#pragma unroll
        for (int tf = 0; tf < 4; ++tf) {
            const int f = f0 + wf * 64 + tf * 16 + m;
            const float bv = bias[f];
            float4 o;
            o.x = acc[tl][tf][0] + bv;
            o.y = acc[tl][tf][1] + bv;
            o.z = acc[tl][tf][2] + bv;
            o.w = acc[tl][tf][3] + bv;
            *(float4*)(out + ((size_t)b * E_DIM + f) * L_SEQ + lb) = o;
        }
    }
}

// ---------------------------------------------------------------------------
extern "C" void kernel_launch(void* const* d_in, const int* in_sizes, int n_in,
                              void* d_out, int out_size, void* d_ws, size_t ws_size,
                              hipStream_t stream) {
    const float* query = (const float*)d_in[0];
    const float* keys  = (const float*)d_in[1];
    const float* vals  = (const float*)d_in[2];
    const int*   rind  = (const int*)d_in[3];
    const float* ipw   = (const float*)d_in[4];
    const float* ipb   = (const float*)d_in[5];
    const float* opw   = (const float*)d_in[6];
    const float* opb   = (const float*)d_in[7];
    float* out = (float*)d_out;

    char* ws = (char*)d_ws;
    const size_t MI = 1024 * 1024;
    float*  qs_pack  = (float*)(ws + 0);             //  2 MiB
    double* minpart  = (double*)(ws + 2 * MI);       //  1 MiB
    int*    sel      = (int*)   (ws + 3 * MI);       //  8 KiB
    short*  khb      = (short*) (ws + 4 * MI);       //  1 MiB
    int*    rankpart = (int*)   (ws + 5 * MI);       //  1 MiB
    short*  vtb      = (short*) (ws + 6 * MI);       //  1 MiB
    short*  wqhi     = (short*) (ws + 7 * MI);       // 128 KiB
    short*  wqlo     = (short*) (ws + 7 * MI + 131072);
    short*  wohi     = (short*) (ws + 7 * MI + 2 * 131072);
    short*  wolo     = (short*) (ws + 7 * MI + 3 * 131072);
    short*  qhb      = (short*) (ws + 8 * MI);       // 16 MiB, live qgemm->attn
    short*  qhi      = (short*) (ws + 24 * MI);      // 16 MiB, dead after qgemm
    short*  qlo      = (short*) (ws + 40 * MI);      // 16 MiB, dead after qgemm
    short*  ohi      = (short*) (ws + 24 * MI);      // overlaps qhi (attn writes after qgemm)
    short*  olo      = (short*) (ws + 40 * MI);      // overlaps qlo

    const float scale = 0.17677669529663687f;  // 32^-0.5

    k_prep<<<dim3(4352), 256, 0, stream>>>(query, rind, ipw, opw, qs_pack,
                                           wqhi, wqlo, wohi, wolo, qhi, qlo);
    k_dist<<<dim3(L_SEQ / 64, NSPLIT, B_SZ), dim3(256), 0, stream>>>(keys, qs_pack, minpart);
    k_rankpart<<<dim3(L_SEQ / 256, JSPL, B_SZ), 256, 0, stream>>>(minpart, rankpart);
    k_sel<<<dim3((B_SZ * L_SEQ) / 256), 256, 0, stream>>>(rankpart, sel);
    k_kvproj2<<<dim3(E_DIM / 64, 2 * (S_TOP / 64), B_SZ), dim3(16, 16), 0, stream>>>(
        keys, vals, sel,
        ipw + (size_t)E_DIM * E_DIM, ipb + E_DIM,
        ipw + (size_t)2 * E_DIM * E_DIM, ipb + 2 * E_DIM,
        khb, vtb);
    k_qgemm<<<dim3(E_DIM / 128, L_SEQ / 128, B_SZ), 256, 0, stream>>>(
        qhi, qlo, wqhi, wqlo, ipb, qhb, scale);
    k_attn<<<dim3(L_SEQ / 16, NHEAD, B_SZ), dim3(64), 0, stream>>>(qhb, khb, vtb, ohi, olo);
    k_ogemm<<<dim3(E_DIM / 128, L_SEQ / 128, B_SZ), 256, 0, stream>>>(
        ohi, olo, wohi, wolo, opb, out);
}

// Round 22
// 417.716 us; speedup vs baseline: 1.0581x; 1.0353x over previous
//
#include <hip/hip_runtime.h>
#include <math.h>

#define B_SZ   8
#define E_DIM  256
#define L_SEQ  4096
#define S_TOP  256
#define NHEAD  8
#define HD     32
#define NSPLIT 4
#define JSPL   8

typedef __attribute__((ext_vector_type(8))) short bf16x8;   // MFMA A/B frag (16B)
typedef __attribute__((ext_vector_type(4))) float f32x4;    // MFMA C/D frag

// async global->LDS, 16B per lane; LDS dest must be wave-linear (base+lane*16)
#define GLDS16(gsrc, ldst) __builtin_amdgcn_global_load_lds( \
    (const __attribute__((address_space(1))) void*)(gsrc),   \
    (__attribute__((address_space(3))) void*)(ldst), 16, 0, 0)

// round-to-nearest-even fp32 -> bf16
__device__ inline short f2bf(float x) {
    union { float f; unsigned u; } v; v.f = x;
    unsigned r = (v.u + 0x7fff + ((v.u >> 16) & 1)) >> 16;
    return (short)r;
}
__device__ inline float bf2f(short h) {
    union { unsigned u; float f; } c; c.u = ((unsigned)(unsigned short)h) << 16;
    return c.f;
}

// ---------------------------------------------------------------------------
// K_prep: gather + qconv + wconv fused (verified).
// grid 4352 = 2048 (gather) + 2048 (qconv) + 256 (wconv).
// ---------------------------------------------------------------------------
__global__ __launch_bounds__(256) void k_prep(const float* __restrict__ query,
                                              const int* __restrict__ ind,
                                              const float* __restrict__ wq,
                                              const float* __restrict__ wo,
                                              float* __restrict__ qs_pack,
                                              short* __restrict__ wqhi,
                                              short* __restrict__ wqlo,
                                              short* __restrict__ wohi,
                                              short* __restrict__ wolo,
                                              short* __restrict__ qhi,
                                              short* __restrict__ qlo) {
    __shared__ float T[64][68];                 // used by qconv section only
    const int blk = blockIdx.x;
    if (blk < 2048) {                           // --- gather ---
        int t = blk * 256 + threadIdx.x;        // over B*S*E = 524288
        int e = t & (E_DIM - 1);
        int s = (t >> 8) & (S_TOP - 1);
        int b = t >> 16;
        int idx = ind[b * S_TOP + s];
        qs_pack[t] = query[((size_t)b * E_DIM + e) * L_SEQ + idx];
        return;
    }
    if (blk >= 4096) {                          // --- wconv ---
        int t = (blk - 4096) * 256 + threadIdx.x;   // 0..65535
        float xq = wq[t];
        short hq = f2bf(xq);
        wqhi[t] = hq;
        wqlo[t] = f2bf(xq - bf2f(hq));
        float xo = wo[t];
        short ho = f2bf(xo);
        wohi[t] = ho;
        wolo[t] = f2bf(xo - bf2f(ho));
        return;
    }
    // --- qconv: transpose+split query [b][e][l] -> qhi/qlo [b][l][e] ---
    const int idx = blk - 2048;                 // 0..2047
    const int b  = idx >> 8;
    const int e0 = ((idx >> 6) & 3) * 64;
    const int l0 = (idx & 63) * 64;
    const float* src = query + ((size_t)b * E_DIM + e0) * L_SEQ + l0;
#pragma unroll
    for (int r = 0; r < 4; ++r) {
        int i2 = threadIdx.x + 256 * r;         // 0..1023
        int e = i2 >> 4, l4 = (i2 & 15) * 4;
        *(float4*)&T[e][l4] = *(const float4*)(src + (size_t)e * L_SEQ + l4);
    }
    __syncthreads();
    const int l  = threadIdx.x >> 2;            // 0..63
    const int ec = (threadIdx.x & 3) * 16;      // 0,16,32,48
    size_t dst = ((size_t)b * L_SEQ + l0 + l) * E_DIM + e0 + ec;
    bf16x8 h0, h1, lo0, lo1;
#pragma unroll
    for (int k = 0; k < 8; ++k) {
        float x = T[ec + k][l];
        short h = f2bf(x);
        h0[k] = h; lo0[k] = f2bf(x - bf2f(h));
    }
#pragma unroll
    for (int k = 0; k < 8; ++k) {
        float x = T[ec + 8 + k][l];
        short h = f2bf(x);
        h1[k] = h; lo1[k] = f2bf(x - bf2f(h));
    }
    *(bf16x8*)(qhi + dst)     = h0;
    *(bf16x8*)(qhi + dst + 8) = h1;
    *(bf16x8*)(qlo + dst)     = lo0;
    *(bf16x8*)(qlo + dst + 8) = lo1;
}

// ---------------------------------------------------------------------------
// K1: async-LDS double-buffered L1-distance (verified 97.5us, clean
// counters, VALU-issue floor; FROZEN). grid (64, NSPLIT, 8).
// ---------------------------------------------------------------------------
__global__ __launch_bounds__(256) void k_dist(const float* __restrict__ keys,
                                              const float* __restrict__ qs_pack,
                                              double* __restrict__ minpart) {
    const int b  = blockIdx.z;
    const int ss = blockIdx.y;
    const int l0 = blockIdx.x * 64;
    const int lid = threadIdx.x;
    const int tx = lid & 15;
    const int ty = lid >> 4;
    __shared__ float Ks[2][32][64];             // 16 KB, off = 16*f4 per buf
    __shared__ float Qs[2][64][32];             // 16 KB, bank-swizzled content
    double (*red)[64] = (double(*)[64])&Ks[0][0][0];   // 8 KB overlay on buf0

    const float* kb = keys + (size_t)b * E_DIM * L_SEQ + l0;
    const float* qb = qs_pack + ((size_t)b * S_TOP + ss * 64) * E_DIM;

    double d[4][4];
#pragma unroll
    for (int i = 0; i < 4; ++i)
#pragma unroll
        for (int j = 0; j < 4; ++j) d[i][j] = 0.0;

    {   // issue chunk-0 loads into buf 0 (Qs source pre-swizzled)
#pragma unroll
        for (int r = 0; r < 2; ++r) {
            int f4 = lid + 256 * r;
            int e  = f4 >> 4, l4 = (f4 & 15) * 4;
            GLDS16(kb + (size_t)e * L_SEQ + l4, &Ks[0][e][l4]);
            int s  = f4 >> 3, e4 = (f4 & 7) * 4;
            int el = e4 ^ (((s >> 2) & 7) << 2);    // logical col for phys e4
            GLDS16(qb + (size_t)s * E_DIM + el, &Qs[0][s][e4]);
        }
    }

    int buf = 0;
    for (int c0 = 0; c0 < E_DIM; c0 += 32, buf ^= 1) {
        __syncthreads();                        // drains vmcnt: chunk-c data
                                                // in LDS; prior compute done
        if (c0 + 32 < E_DIM) {                  // issue c+1 into other buffer;
            const int cn = c0 + 32;             // flies during compute below
            const int nb = buf ^ 1;
#pragma unroll
            for (int r = 0; r < 2; ++r) {
                int f4 = lid + 256 * r;
                int e  = f4 >> 4, l4 = (f4 & 15) * 4;
                GLDS16(kb + (size_t)(cn + e) * L_SEQ + l4, &Ks[nb][e][l4]);
                int s  = f4 >> 3, e4 = (f4 & 7) * 4;
                int el = e4 ^ (((s >> 2) & 7) << 2);
                GLDS16(qb + (size_t)s * E_DIM + cn + el, &Qs[nb][s][e4]);
            }
        }

        float cs[4][4] = {};                    // 16 indep fp32 chains
#pragma unroll
        for (int e4 = 0; e4 < 32; e4 += 4) {
            float qv[4][4];
#pragma unroll
            for (int j = 0; j < 4; ++j) {       // swizzled b128 reads: the 4
                const int row = ty * 4 + j;     // ty-groups hit disjoint banks
                float4 q = *(const float4*)&Qs[buf][row][e4 ^ (((row >> 2) & 7) << 2)];
                qv[j][0] = q.x; qv[j][1] = q.y; qv[j][2] = q.z; qv[j][3] = q.w;
            }
#pragma unroll
            for (int ee = 0; ee < 4; ++ee) {    // e ascending: e4+0,1,2,3
                float kv[4];
#pragma unroll
                for (int i = 0; i < 4; ++i) kv[i] = Ks[buf][e4 + ee][tx * 4 + i];
#pragma unroll
                for (int i = 0; i < 4; ++i)
#pragma unroll
                    for (int j = 0; j < 4; ++j)
                        cs[i][j] += fabsf(kv[i] - qv[j][ee]);
            }
        }
#pragma unroll
        for (int i = 0; i < 4; ++i)
#pragma unroll
            for (int j = 0; j < 4; ++j) d[i][j] += (double)cs[i][j];
    }

    // per-thread exact f64 min over its 4 s
    double md[4];
#pragma unroll
    for (int i = 0; i < 4; ++i) {
        double m = d[i][0];
        m = fmin(m, d[i][1]);
        m = fmin(m, d[i][2]);
        m = fmin(m, d[i][3]);
        md[i] = m;
    }
    __syncthreads();                            // all buf reads done
#pragma unroll
    for (int i = 0; i < 4; ++i) red[ty][tx * 4 + i] = md[i];
    __syncthreads();
    if (lid < 64) {                             // cross-thread min over 16 ty
        double m = red[0][lid];
#pragma unroll
        for (int t = 1; t < 16; ++t) m = fmin(m, red[t][lid]);
        minpart[((size_t)(b * NSPLIT + ss)) * L_SEQ + l0 + lid] = m;
    }
}

// ---------------------------------------------------------------------------
// K2a: partial rank (UNCHANGED)
// ---------------------------------------------------------------------------
__global__ __launch_bounds__(256) void k_rankpart(const double* __restrict__ minpart,
                                                  int* __restrict__ rankpart) {
    const int b  = blockIdx.z;
    const int js = blockIdx.y;
    const int l  = blockIdx.x * 256 + threadIdx.x;
    __shared__ double sd[512];
    const double* mp = minpart + (size_t)b * NSPLIT * L_SEQ;
    for (int jj = threadIdx.x; jj < 512; jj += 256) {
        const int j = js * 512 + jj;
        double v = mp[j];
        v = fmin(v, mp[L_SEQ + j]);
        v = fmin(v, mp[2 * L_SEQ + j]);
        v = fmin(v, mp[3 * L_SEQ + j]);
        sd[jj] = v;
    }
    double dl = mp[l];
    dl = fmin(dl, mp[L_SEQ + l]);
    dl = fmin(dl, mp[2 * L_SEQ + l]);
    dl = fmin(dl, mp[3 * L_SEQ + l]);
    __syncthreads();
    const int jbase = js * 512;
    int rank = 0;
#pragma unroll 8
    for (int jj = 0; jj < 512; ++jj) {
        double dj = sd[jj];
        rank += (dj < dl) || (dj == dl && (jbase + jj) < l) ? 1 : 0;
    }
    rankpart[((size_t)(b * JSPL + js)) * L_SEQ + l] = rank;
}

// ---------------------------------------------------------------------------
// K2b: combine ranks, scatter (UNCHANGED)
// ---------------------------------------------------------------------------
__global__ __launch_bounds__(256) void k_sel(const int* __restrict__ rankpart,
                                             int* __restrict__ sel) {
    const int t = blockIdx.x * 256 + threadIdx.x;
    const int b = t >> 12;
    const int l = t & (L_SEQ - 1);
    int r = 0;
#pragma unroll
    for (int s = 0; s < JSPL; ++s)
        r += rankpart[((size_t)(b * JSPL + s)) * L_SEQ + l];
    if (r < S_TOP) sel[b * S_TOP + r] = l;
}

// ---------------------------------------------------------------------------
// K3: K/V projection merged (UNCHANGED)
// ---------------------------------------------------------------------------
__global__ __launch_bounds__(256) void k_kvproj2(const float* __restrict__ keys,
                                                 const float* __restrict__ vals,
                                                 const int* __restrict__ sel,
                                                 const float* __restrict__ Wk,
                                                 const float* __restrict__ bk,
                                                 const float* __restrict__ Wv,
                                                 const float* __restrict__ bv,
                                                 short* __restrict__ khb,
                                                 short* __restrict__ vtb) {
    const int b  = blockIdx.z;
    const int f0 = blockIdx.x * 64;
    const int TR = blockIdx.y >> 2;
    const int k0 = (blockIdx.y & 3) * 64;
    const float* src  = TR ? vals : keys;
    const float* W    = TR ? Wv : Wk;
    const float* bias = TR ? bv : bk;
    const int tx = threadIdx.x, ty = threadIdx.y;
    const int lid = ty * 16 + tx;
    __shared__ float As[16][68];
    __shared__ float Ws[16][68];
    float c[4][4] = {};
    const float* sb = src + (size_t)b * E_DIM * L_SEQ;
    const int* selb = sel + b * S_TOP;
    for (int e0 = 0; e0 < E_DIM; e0 += 16) {
        {
            int e  = lid >> 4;
            int k4 = (lid & 15) * 4;
#pragma unroll
            for (int c2 = 0; c2 < 4; ++c2) {
                int kk = k4 + c2;
                As[e][kk] = sb[(size_t)(e0 + e) * L_SEQ + selb[k0 + kk]];
            }
        }
        {
            int f  = lid >> 2;
            int e4 = (lid & 3) * 4;
            float4 w = *(const float4*)(W + (size_t)(f0 + f) * E_DIM + e0 + e4);
            Ws[e4 + 0][f] = w.x; Ws[e4 + 1][f] = w.y;
            Ws[e4 + 2][f] = w.z; Ws[e4 + 3][f] = w.w;
        }
        __syncthreads();
#pragma unroll
        for (int e = 0; e < 16; ++e) {
            float4 a = *(const float4*)&As[e][ty * 4];
            float4 w = *(const float4*)&Ws[e][tx * 4];
            float av[4] = {a.x, a.y, a.z, a.w};
            float wv[4] = {w.x, w.y, w.z, w.w};
#pragma unroll
            for (int i = 0; i < 4; ++i)
#pragma unroll
                for (int j = 0; j < 4; ++j) c[i][j] += av[i] * wv[j];
        }
        __syncthreads();
    }
    if (TR == 0) {
#pragma unroll
        for (int i = 0; i < 4; ++i) {
            short4 o;
            o.x = f2bf(c[i][0] + bias[f0 + tx * 4 + 0]);
            o.y = f2bf(c[i][1] + bias[f0 + tx * 4 + 1]);
            o.z = f2bf(c[i][2] + bias[f0 + tx * 4 + 2]);
            o.w = f2bf(c[i][3] + bias[f0 + tx * 4 + 3]);
            *(short4*)(khb + ((size_t)b * S_TOP + k0 + ty * 4 + i) * E_DIM + f0 + tx * 4) = o;
        }
    } else {
#pragma unroll
        for (int j = 0; j < 4; ++j) {
            const float bvv = bias[f0 + tx * 4 + j];
            short4 o;
            o.x = f2bf(c[0][j] + bvv); o.y = f2bf(c[1][j] + bvv);
            o.z = f2bf(c[2][j] + bvv); o.w = f2bf(c[3][j] + bvv);
            *(short4*)(vtb + ((size_t)b * E_DIM + f0 + tx * 4 + j) * S_TOP + k0 + ty * 4) = o;
        }
    }
}

// ---------------------------------------------------------------------------
// K_qgemm: qhb[b][l][f] = bf16(scale*(q @ Wq^T + bq)) via split-bf16 MFMA
// (UNCHANGED).
// ---------------------------------------------------------------------------
__global__ __launch_bounds__(256) void k_qgemm(const short* __restrict__ qhi,
                                               const short* __restrict__ qlo,
                                               const short* __restrict__ wqhi,
                                               const short* __restrict__ wqlo,
                                               const float* __restrict__ bias,
                                               short* __restrict__ qhb,
                                               float scale) {
    const int b  = blockIdx.z;
    const int f0 = blockIdx.x * 128;
    const int l0 = blockIdx.y * 128;
    const int lid  = threadIdx.x;
    const int wv   = lid >> 6;
    const int lane = lid & 63;
    const int quad = lane >> 4;
    const int m    = lane & 15;
    const int wf   = wv >> 1;
    const int wl   = wv & 1;

    __shared__ short Awh[128 * 40];
    __shared__ short Awl[128 * 40];
    __shared__ short Bqh[128 * 40];
    __shared__ short Bql[128 * 40];

    const short* wh_g = wqhi + (size_t)f0 * E_DIM;
    const short* wl_g = wqlo + (size_t)f0 * E_DIM;
    const short* qh_g = qhi + ((size_t)b * L_SEQ + l0) * E_DIM;
    const short* ql_g = qlo + ((size_t)b * L_SEQ + l0) * E_DIM;

    f32x4 acc[4][4];
    const f32x4 zero = {0.f, 0.f, 0.f, 0.f};
#pragma unroll
    for (int i = 0; i < 4; ++i)
#pragma unroll
        for (int j = 0; j < 4; ++j) acc[i][j] = zero;

    for (int k0 = 0; k0 < E_DIM; k0 += 32) {
        __syncthreads();
#pragma unroll
        for (int r = 0; r < 2; ++r) {
            int idx = lid + 256 * r;            // 0..511
            int row = idx >> 2;
            int kc  = (idx & 3) * 8;
            *(bf16x8*)&Awh[row * 40 + kc] = *(const bf16x8*)(wh_g + (size_t)row * E_DIM + k0 + kc);
            *(bf16x8*)&Awl[row * 40 + kc] = *(const bf16x8*)(wl_g + (size_t)row * E_DIM + k0 + kc);
            *(bf16x8*)&Bqh[row * 40 + kc] = *(const bf16x8*)(qh_g + (size_t)row * E_DIM + k0 + kc);
            *(bf16x8*)&Bql[row * 40 + kc] = *(const bf16x8*)(ql_g + (size_t)row * E_DIM + k0 + kc);
        }
        __syncthreads();

        bf16x8 ah[4], al[4], bh[4], bl[4];
#pragma unroll
        for (int tf = 0; tf < 4; ++tf) {
            int row = wf * 64 + tf * 16 + m;
            ah[tf] = *(const bf16x8*)&Awh[row * 40 + quad * 8];
            al[tf] = *(const bf16x8*)&Awl[row * 40 + quad * 8];
        }
#pragma unroll
        for (int tl = 0; tl < 4; ++tl) {
            int row = wl * 64 + tl * 16 + m;
            bh[tl] = *(const bf16x8*)&Bqh[row * 40 + quad * 8];
            bl[tl] = *(const bf16x8*)&Bql[row * 40 + quad * 8];
        }
#pragma unroll
        for (int tf = 0; tf < 4; ++tf)
#pragma unroll
            for (int tl = 0; tl < 4; ++tl) {
                acc[tf][tl] = __builtin_amdgcn_mfma_f32_16x16x32_bf16(al[tf], bh[tl], acc[tf][tl], 0, 0, 0);
                acc[tf][tl] = __builtin_amdgcn_mfma_f32_16x16x32_bf16(ah[tf], bl[tl], acc[tf][tl], 0, 0, 0);
                acc[tf][tl] = __builtin_amdgcn_mfma_f32_16x16x32_bf16(ah[tf], bh[tl], acc[tf][tl], 0, 0, 0);
            }
    }

#pragma unroll
    for (int tf = 0; tf < 4; ++tf) {
        const int fb = f0 + wf * 64 + tf * 16 + quad * 4;
        float bv0 = bias[fb + 0], bv1 = bias[fb + 1];
        float bv2 = bias[fb + 2], bv3 = bias[fb + 3];
#pragma unroll
        for (int tl = 0; tl < 4; ++tl) {
            const int l = l0 + wl * 64 + tl * 16 + m;
            short4 o;
            o.x = f2bf(scale * (acc[tf][tl][0] + bv0));
            o.y = f2bf(scale * (acc[tf][tl][1] + bv1));
            o.z = f2bf(scale * (acc[tf][tl][2] + bv2));
            o.w = f2bf(scale * (acc[tf][tl][3] + bv3));
            *(short4*)(qhb + ((size_t)b * L_SEQ + l) * E_DIM + fb) = o;
        }
    }
}

// ---------------------------------------------------------------------------
// K4: bf16 MFMA flash attention v3. r19 PMC: 74.5us, MfmaUtil 4.3%,
// VALUBusy 28%, Occ 27%; r20 occupancy fix NEUTRAL -> stall is within-wave
// dependent-chain latency on scattered L2 K loads. Fix: block cooperatively
// stages the K h-slice (256x32 bf16) into padded LDS Kl[256][40] ONCE
// (reg-staged; pad -> frag reads ~2-way/free); QK^T reads K from LDS. V
// stays global (independent loads overlap PV MFMAs). Values copied exactly,
// MFMA order unchanged -> bit-identical. LDS 20.5K+33.8K=54.3KB (~3/CU).
// grid (L/64, H, B), block 256 (4 waves).
// ---------------------------------------------------------------------------
__global__ __launch_bounds__(256) void k_attn(const short* __restrict__ qhb,
                                              const short* __restrict__ khb,
                                              const short* __restrict__ vtb,
                                              short* __restrict__ ohi,
                                              short* __restrict__ olo) {
    __shared__ short Kl[256][40];               // 20.5 KB, K h-slice, padded
    __shared__ short P[4][16][264];             // 33.8 KB, wave-private
    const int b = blockIdx.z, h = blockIdx.y;
    const int lid  = threadIdx.x;
    const int wv   = lid >> 6;
    const int lane = lid & 63;
    const int quad = lane >> 4;
    const int m    = lane & 15;
    const int l0 = blockIdx.x * 64 + wv * 16;

    // cooperative K stage: 256 rows x 32 cols -> Kl (exact copy)
    const short* kg = khb + (size_t)b * S_TOP * E_DIM + h * HD;
    {
        bf16x8 tmp[4];
#pragma unroll
        for (int r = 0; r < 4; ++r) {
            int idx = lid + 256 * r;            // 0..1023
            int row = idx >> 2, slot = idx & 3;
            tmp[r] = *(const bf16x8*)(kg + (size_t)row * E_DIM + slot * 8);
        }
#pragma unroll
        for (int r = 0; r < 4; ++r) {
            int idx = lid + 256 * r;
            int row = idx >> 2, slot = idx & 3;
            *(bf16x8*)&Kl[row][slot * 8] = tmp[r];
        }
    }
    const short* qp = qhb + ((size_t)b * L_SEQ + l0 + m) * E_DIM + h * HD + quad * 8;
    const bf16x8 qa = *(const bf16x8*)qp;       // overlaps with stage drain
    __syncthreads();                            // Kl visible to all waves

    f32x4 sacc[16];
    const f32x4 zero = {0.f, 0.f, 0.f, 0.f};
#pragma unroll
    for (int t = 0; t < 16; ++t) {
        bf16x8 kf = *(const bf16x8*)&Kl[t * 16 + m][quad * 8];
        sacc[t] = __builtin_amdgcn_mfma_f32_16x16x32_bf16(qa, kf, zero, 0, 0, 0);
    }

    float mx[4], ssum[4];
#pragma unroll
    for (int r = 0; r < 4; ++r) {
        float v = sacc[0][r];
#pragma unroll
        for (int t = 1; t < 16; ++t) v = fmaxf(v, sacc[t][r]);
#pragma unroll
        for (int off = 1; off < 16; off <<= 1) v = fmaxf(v, __shfl_xor(v, off, 16));
        mx[r] = v;
        ssum[r] = 0.f;
    }
#pragma unroll
    for (int t = 0; t < 16; ++t) {
#pragma unroll
        for (int r = 0; r < 4; ++r) {
            float p = __expf(sacc[t][r] - mx[r]);
            ssum[r] += p;
            P[wv][quad * 4 + r][t * 16 + m] = f2bf(p);
        }
    }
#pragma unroll
    for (int r = 0; r < 4; ++r) {
        float v = ssum[r];
#pragma unroll
        for (int off = 1; off < 16; off <<= 1) v += __shfl_xor(v, off, 16);
        ssum[r] = v;
    }

    const short* vb = vtb + ((size_t)b * E_DIM + h * HD) * S_TOP;
    f32x4 oacc[2];
#pragma unroll
    for (int dt = 0; dt < 2; ++dt) {
        f32x4 acc = zero;
#pragma unroll
        for (int k0 = 0; k0 < S_TOP; k0 += 32) {
            bf16x8 pa = *(const bf16x8*)&P[wv][m][k0 + quad * 8];
            bf16x8 vf = *(const bf16x8*)(vb + (size_t)(dt * 16 + m) * S_TOP + k0 + quad * 8);
            acc = __builtin_amdgcn_mfma_f32_16x16x32_bf16(pa, vf, acc, 0, 0, 0);
        }
        oacc[dt] = acc;
    }

    short* oph = ohi + ((size_t)b * L_SEQ + l0) * E_DIM + h * HD;
    short* opl = olo + ((size_t)b * L_SEQ + l0) * E_DIM + h * HD;
#pragma unroll
    for (int r = 0; r < 4; ++r) {
        const float inv = 1.0f / ssum[r];
#pragma unroll
        for (int dt = 0; dt < 2; ++dt) {
            float val = oacc[dt][r] * inv;
            short hh = f2bf(val);
            size_t off = (size_t)(quad * 4 + r) * E_DIM + dt * 16 + m;
            oph[off] = hh;
            opl[off] = f2bf(val - bf2f(hh));
        }
    }
}

// ---------------------------------------------------------------------------
// K_ogemm: out[b][f][l] = o @ Wout^T + b_out via split-bf16 MFMA (UNCHANGED).
// ---------------------------------------------------------------------------
__global__ __launch_bounds__(256) void k_ogemm(const short* __restrict__ ohi,
                                               const short* __restrict__ olo,
                                               const short* __restrict__ wohi,
                                               const short* __restrict__ wolo,
                                               const float* __restrict__ bias,
                                               float* __restrict__ out) {
    const int b  = blockIdx.z;
    const int f0 = blockIdx.x * 128;
    const int l0 = blockIdx.y * 128;
    const int lid  = threadIdx.x;
    const int wv   = lid >> 6;
    const int lane = lid & 63;
    const int quad = lane >> 4;
    const int m    = lane & 15;
    const int wl   = wv >> 1;
    const int wf   = wv & 1;

    __shared__ short Aoh[128 * 40];
    __shared__ short Aol[128 * 40];
    __shared__ short Bwh[128 * 40];
    __shared__ short Bwl[128 * 40];

    const short* oh_g = ohi + ((size_t)b * L_SEQ + l0) * E_DIM;
    const short* ol_g = olo + ((size_t)b * L_SEQ + l0) * E_DIM;
    const short* wh_g = wohi + (size_t)f0 * E_DIM;
    const short* wl_g = wolo + (size_t)f0 * E_DIM;

    f32x4 acc[4][4];
    const f32x4 zero = {0.f, 0.f, 0.f, 0.f};
#pragma unroll
    for (int i = 0; i < 4; ++i)
#pragma unroll
        for (int j = 0; j < 4; ++j) acc[i][j] = zero;

    for (int k0 = 0; k0 < E_DIM; k0 += 32) {
        __syncthreads();
#pragma unroll
        for (int r = 0; r < 2; ++r) {
            int idx = lid + 256 * r;
            int row = idx >> 2;
            int kc  = (idx & 3) * 8;
            *(bf16x8*)&Aoh[row * 40 + kc] = *(const bf16x8*)(oh_g + (size_t)row * E_DIM + k0 + kc);
            *(bf16x8*)&Aol[row * 40 + kc] = *(const bf16x8*)(ol_g + (size_t)row * E_DIM + k0 + kc);
            *(bf16x8*)&Bwh[row * 40 + kc] = *(const bf16x8*)(wh_g + (size_t)row * E_DIM + k0 + kc);
            *(bf16x8*)&Bwl[row * 40 + kc] = *(const bf16x8*)(wl_g + (size_t)row * E_DIM + k0 + kc);
        }
        __syncthreads();

        bf16x8 ah[4], al[4], bh[4], bl[4];
#pragma unroll
        for (int tl = 0; tl < 4; ++tl) {
            int row = wl * 64 + tl * 16 + m;
            ah[tl] = *(const bf16x8*)&Aoh[row * 40 + quad * 8];
            al[tl] = *(const bf16x8*)&Aol[row * 40 + quad * 8];
        }
#pragma unroll
        for (int tf = 0; tf < 4; ++tf) {
            int row = wf * 64 + tf * 16 + m;
            bh[tf] = *(const bf16x8*)&Bwh[row * 40 + quad * 8];
            bl[tf] = *(const bf16x8*)&Bwl[row * 40 + quad * 8];
        }
#pragma unroll
        for (int tl = 0; tl < 4; ++tl)
#pragma unroll
            for (int tf = 0; tf < 4; ++tf) {
                acc[tl][tf] = __builtin_amdgcn_mfma_f32_16x16x32_bf16(al[tl], bh[tf], acc[tl][tf], 0, 0, 0);
                acc[tl][tf] = __builtin_amdgcn_mfma_f32_16x16x32_bf16(ah[tl], bl[tf], acc[tl][tf], 0, 0, 0);
                acc[tl][tf] = __builtin_amdgcn_mfma_f32_16x16x32_bf16(ah[tl], bh[tf], acc[tl][tf], 0, 0, 0);
            }
    }

#pragma unroll
    for (int tl = 0; tl < 4; ++tl) {
        const int lb = l0 + wl * 64 + tl * 16 + quad * 4;
#pragma unroll
        for (int tf = 0; tf < 4; ++tf) {
            const int f = f0 + wf * 64 + tf * 16 + m;
            const float bv = bias[f];
            float4 o;
            o.x = acc[tl][tf][0] + bv;
            o.y = acc[tl][tf][1] + bv;
            o.z = acc[tl][tf][2] + bv;
            o.w = acc[tl][tf][3] + bv;
            *(float4*)(out + ((size_t)b * E_DIM + f) * L_SEQ + lb) = o;
        }
    }
}

// ---------------------------------------------------------------------------
extern "C" void kernel_launch(void* const* d_in, const int* in_sizes, int n_in,
                              void* d_out, int out_size, void* d_ws, size_t ws_size,
                              hipStream_t stream) {
    const float* query = (const float*)d_in[0];
    const float* keys  = (const float*)d_in[1];
    const float* vals  = (const float*)d_in[2];
    const int*   rind  = (const int*)d_in[3];
    const float* ipw   = (const float*)d_in[4];
    const float* ipb   = (const float*)d_in[5];
    const float* opw   = (const float*)d_in[6];
    const float* opb   = (const float*)d_in[7];
    float* out = (float*)d_out;

    char* ws = (char*)d_ws;
    const size_t MI = 1024 * 1024;
    float*  qs_pack  = (float*)(ws + 0);             //  2 MiB
    double* minpart  = (double*)(ws + 2 * MI);       //  1 MiB
    int*    sel      = (int*)   (ws + 3 * MI);       //  8 KiB
    short*  khb      = (short*) (ws + 4 * MI);       //  1 MiB
    int*    rankpart = (int*)   (ws + 5 * MI);       //  1 MiB
    short*  vtb      = (short*) (ws + 6 * MI);       //  1 MiB
    short*  wqhi     = (short*) (ws + 7 * MI);       // 128 KiB
    short*  wqlo     = (short*) (ws + 7 * MI + 131072);
    short*  wohi     = (short*) (ws + 7 * MI + 2 * 131072);
    short*  wolo     = (short*) (ws + 7 * MI + 3 * 131072);
    short*  qhb      = (short*) (ws + 8 * MI);       // 16 MiB, live qgemm->attn
    short*  qhi      = (short*) (ws + 24 * MI);      // 16 MiB, dead after qgemm
    short*  qlo      = (short*) (ws + 40 * MI);      // 16 MiB, dead after qgemm
    short*  ohi      = (short*) (ws + 24 * MI);      // overlaps qhi (attn writes after qgemm)
    short*  olo      = (short*) (ws + 40 * MI);      // overlaps qlo

    const float scale = 0.17677669529663687f;  // 32^-0.5

    k_prep<<<dim3(4352), 256, 0, stream>>>(query, rind, ipw, opw, qs_pack,
                                           wqhi, wqlo, wohi, wolo, qhi, qlo);
    k_dist<<<dim3(L_SEQ / 64, NSPLIT, B_SZ), dim3(256), 0, stream>>>(keys, qs_pack, minpart);
    k_rankpart<<<dim3(L_SEQ / 256, JSPL, B_SZ), 256, 0, stream>>>(minpart, rankpart);
    k_sel<<<dim3((B_SZ * L_SEQ) / 256), 256, 0, stream>>>(rankpart, sel);
    k_kvproj2<<<dim3(E_DIM / 64, 2 * (S_TOP / 64), B_SZ), dim3(16, 16), 0, stream>>>(
        keys, vals, sel,
        ipw + (size_t)E_DIM * E_DIM, ipb + E_DIM,
        ipw + (size_t)2 * E_DIM * E_DIM, ipb + 2 * E_DIM,
        khb, vtb);
    k_qgemm<<<dim3(E_DIM / 128, L_SEQ / 128, B_SZ), 256, 0, stream>>>(
        qhi, qlo, wqhi, wqlo, ipb, qhb, scale);
    k_attn<<<dim3(L_SEQ / 64, NHEAD, B_SZ), 256, 0, stream>>>(qhb, khb, vtb, ohi, olo);
    k_ogemm<<<dim3(E_DIM / 128, L_SEQ / 128, B_SZ), 256, 0, stream>>>(
        ohi, olo, wohi, wolo, opb, out);
}